// Round 4
// baseline (1026.071 us; speedup 1.0000x reference)
//
#include <hip/hip_runtime.h>
#include <hip/hip_bf16.h>

typedef float f32x4 __attribute__((ext_vector_type(4)));
typedef short short8 __attribute__((ext_vector_type(8)));
typedef __bf16 bf16x8 __attribute__((ext_vector_type(8)));
typedef unsigned int u32x4 __attribute__((ext_vector_type(4)));

#define DI __device__ __forceinline__

constexpr int Bsz = 64;
constexpr int Fd  = 1024;
constexpr int Seq = 256;
constexpr int G4  = 4096;
constexpr int Mrows = Seq * Bsz;

DI float bf2f(unsigned short u) {
  union { unsigned int i; float f; } v; v.i = ((unsigned int)u) << 16; return v.f;
}
DI unsigned short f2bf(float f) {
  union { float ff; unsigned int i; } v; v.ff = f;
  unsigned int x = v.i;
  return (unsigned short)((x + 0x7fffu + ((x >> 16) & 1u)) >> 16);
}
DI float sigm(float x) { return 1.f / (1.f + __expf(-x)); }
DI float tanhfast(float x) {
  float e = __expf(-2.f * fabsf(x));
  float t = (1.f - e) / (1.f + e);
  return x < 0.f ? -t : t;
}
DI f32x4 mfma16(short8 a, short8 b, f32x4 c) {
  return __builtin_amdgcn_mfma_f32_16x16x32_bf16(
      __builtin_bit_cast(bf16x8, a), __builtin_bit_cast(bf16x8, b), c, 0, 0, 0);
}

// 4 coherent 16B loads issued in parallel, one waitcnt (MALL round trip).
DI void ld4x4_sys(const unsigned int* p0, const unsigned int* p1,
                  const unsigned int* p2, const unsigned int* p3,
                  u32x4& a, u32x4& b, u32x4& c, u32x4& d) {
  asm volatile(
      "global_load_dwordx4 %0, %4, off sc0 sc1\n\t"
      "global_load_dwordx4 %1, %5, off sc0 sc1\n\t"
      "global_load_dwordx4 %2, %6, off sc0 sc1\n\t"
      "global_load_dwordx4 %3, %7, off sc0 sc1\n\t"
      "s_waitcnt vmcnt(0)"
      : "=&v"(a), "=&v"(b), "=&v"(c), "=&v"(d)
      : "v"(p0), "v"(p1), "v"(p2), "v"(p3)
      : "memory");
}

// ---------- transpose x [B][F][S] f32 -> xs [S][B][F] bf16 ----------
__global__ void k_tx(const float* __restrict__ x, unsigned short* __restrict__ xs) {
  __shared__ float t[32][33];
  int b = blockIdx.z, f0 = blockIdx.y * 32, s0 = blockIdx.x * 32;
  int tx = threadIdx.x & 31, ty = threadIdx.x >> 5;
  const float* src = x + ((size_t)b * Fd + f0) * Seq + s0;
#pragma unroll
  for (int i = 0; i < 32; i += 8)
    t[ty + i][tx] = src[(size_t)(ty + i) * Seq + tx];
  __syncthreads();
#pragma unroll
  for (int i = 0; i < 32; i += 8) {
    int s = s0 + ty + i, f = f0 + tx;
    xs[((size_t)s * Bsz + b) * Fd + f] = f2bf(t[tx][ty + i]);
  }
}

// ---------- transpose-convert [1024][4096] f32 -> [4096][1024] bf16 ----------
__global__ void k_tw(const float* __restrict__ in, unsigned short* __restrict__ out) {
  __shared__ float t[32][33];
  int n0 = blockIdx.x * 32, k0 = blockIdx.y * 32;
  int tx = threadIdx.x & 31, ty = threadIdx.x >> 5;
#pragma unroll
  for (int i = 0; i < 32; i += 8)
    t[ty + i][tx] = in[(size_t)(k0 + ty + i) * G4 + n0 + tx];
  __syncthreads();
#pragma unroll
  for (int i = 0; i < 32; i += 8)
    out[(size_t)(n0 + ty + i) * 1024 + k0 + tx] = f2bf(t[tx][ty + i]);
}

__global__ void k_zero(unsigned int* p, int n) {
  int i = blockIdx.x * 256 + threadIdx.x;
  if (i < n) p[i] = 0u;
}

// ---------- GEMM: C[16384][4096] bf16 = A[16384][1024] x Bt[4096][1024]^T ----------
__launch_bounds__(256, 2)
__global__ void k_gemm(const unsigned short* __restrict__ A,
                       const unsigned short* __restrict__ Bt,
                       unsigned short* __restrict__ C) {
  __shared__ unsigned short a_lds[128 * 64];
  __shared__ unsigned short b_lds[128 * 64];
  int bid = blockIdx.x;
  int tm = bid & 127, tn = bid >> 7;
  int tid = threadIdx.x, w = tid >> 6, l = tid & 63;
  int wm = w >> 1, wn = w & 1;
  f32x4 acc[4][4] = {};
  const unsigned short* Ab = A + (size_t)(tm * 128) * 1024;
  const unsigned short* Bb = Bt + (size_t)(tn * 128) * 1024;
  for (int kt = 0; kt < 16; ++kt) {
#pragma unroll
    for (int i = 0; i < 4; ++i) {
      int ci = tid + i * 256;
      int row = ci >> 3;
      int kB = (ci & 7) * 16;
      short8 va = *(const short8*)((const char*)(Ab + (size_t)row * 1024 + kt * 64) + kB);
      short8 vb = *(const short8*)((const char*)(Bb + (size_t)row * 1024 + kt * 64) + kB);
      int dst = row * 128 + (kB ^ ((row & 7) << 4));
      *(short8*)((char*)a_lds + dst) = va;
      *(short8*)((char*)b_lds + dst) = vb;
    }
    __syncthreads();
#pragma unroll
    for (int kb = 0; kb < 2; ++kb) {
      short8 af[4], bfv[4];
      int kByte = (kb * 32 + ((l >> 4) << 3)) * 2;
#pragma unroll
      for (int mi = 0; mi < 4; ++mi) {
        int row = wm * 64 + mi * 16 + (l & 15);
        af[mi] = *(const short8*)((const char*)a_lds + row * 128 + (kByte ^ ((row & 7) << 4)));
      }
#pragma unroll
      for (int ni = 0; ni < 4; ++ni) {
        int row = wn * 64 + ni * 16 + (l & 15);
        bfv[ni] = *(const short8*)((const char*)b_lds + row * 128 + (kByte ^ ((row & 7) << 4)));
      }
#pragma unroll
      for (int mi = 0; mi < 4; ++mi)
#pragma unroll
        for (int ni = 0; ni < 4; ++ni)
          acc[mi][ni] = mfma16(af[mi], bfv[ni], acc[mi][ni]);
    }
    __syncthreads();
  }
#pragma unroll
  for (int mi = 0; mi < 4; ++mi)
#pragma unroll
    for (int ni = 0; ni < 4; ++ni)
#pragma unroll
      for (int r = 0; r < 4; ++r) {
        int m = tm * 128 + wm * 64 + mi * 16 + ((l >> 4) << 2) + r;
        int n = tn * 128 + wn * 64 + ni * 16 + (l & 15);
        C[(size_t)m * G4 + n] = f2bf(acc[mi][ni][r]);
      }
}

// ---------- recurrence ----------
// 128 blocks: rg = bid&3 (16 batch rows), ch = bid>>2 (32 hidden cols).
// 512 threads = 8 waves; wave w = (gate g = w>>1, col-half cs = w&1).
// Each wave: 16x16 output tile, K=1024, U frags in 128 VGPR/thread.
// Protocol (round-2 proven): system-scope (sc0 sc1, MALL-coherent) relaxed
// atomics for h + tags; store-drain via s_waitcnt vmcnt(0) before tag bump.
__launch_bounds__(512, 2)
__global__ void k_rec(const unsigned short* __restrict__ xs,
                      const unsigned short* __restrict__ xWb,
                      const unsigned short* __restrict__ Ubt,
                      const float* __restrict__ bias,
                      unsigned int* __restrict__ hbuf,  // [2][64][512] dwords
                      unsigned int* __restrict__ tags,  // [4][32]
                      float* __restrict__ out) {
  __shared__ unsigned short h_lds[16 * 1024];  // 32KB swizzled
  __shared__ float g_lds[16][132];             // 8.4KB (+4 pad: banks spread)
  __shared__ float obuf[512][9];               // 18KB out staging
  int bid = blockIdx.x;
  int rg = bid & 3, ch = bid >> 2;
  int tid = threadIdx.x, w = tid >> 6, l = tid & 63;
  int g = w >> 1, cs = w & 1;
  int jloc = cs * 16 + (l & 15);            // 0..31 within chunk
  int ncol = g * 1024 + ch * 32 + jloc;     // gate-col
  int mrow0 = (l >> 4) << 2;                // acc row base (0,4,8,12)

  // preload U fragments: 32 x short8 = 128 VGPR
  const unsigned short* Urow = Ubt + (size_t)ncol * 1024;
  short8 ufr[32];
#pragma unroll
  for (int kb = 0; kb < 32; ++kb)
    ufr[kb] = *(const short8*)(Urow + kb * 32 + ((l >> 4) << 3));
  float bias_l = bias[ncol];

  unsigned int* mytags = tags + rg * 32;
  unsigned int* mytag = mytags + ch;

  int prow = tid >> 5, pj = tid & 31;  // pointwise: 16 rows x 32 cols = 512
  int pb = rg * 16 + prow;
  int pjglob = ch * 32 + pj;

  for (int t = 0; t < Seq; ++t) {
    // prefetch xW rows and x_t (cached loads; latency hides under the spin)
    float xw[4];
#pragma unroll
    for (int r = 0; r < 4; ++r)
      xw[r] = bf2f(xWb[((size_t)t * 64 + rg * 16 + mrow0 + r) * G4 + ncol]);
    float xt = bf2f(xs[((size_t)t * 64 + pb) * Fd + pjglob]);

    f32x4 acc0 = {0.f, 0.f, 0.f, 0.f}, acc1 = {0.f, 0.f, 0.f, 0.f};
    if (t > 0) {
      // wait for all 32 producers of this rowgroup
      if (tid < 32) {
        while (__hip_atomic_load(&mytags[tid], __ATOMIC_RELAXED,
                                 __HIP_MEMORY_SCOPE_SYSTEM) < (unsigned int)t) {}
      }
      __syncthreads();
      // coherent read of h(t-1): 16 rows x 512 dwords = 32KB, 64B/thread
      const unsigned int* hp = hbuf + (((t & 1) ^ 1) << 15) + (rg << 13);
      u32x4 h0, h1, h2, h3;
      ld4x4_sys(hp + tid * 4, hp + 2048 + tid * 4, hp + 4096 + tid * 4,
                hp + 6144 + tid * 4, h0, h1, h2, h3);
      __builtin_amdgcn_sched_barrier(0);
      {
        int c0 = tid;        int r0 = c0 >> 7, b0 = (c0 & 127) * 16;
        *(u32x4*)((char*)h_lds + r0 * 2048 + (b0 ^ ((r0 & 7) << 4))) = h0;
        int c1 = tid + 512;  int r1 = c1 >> 7, b1 = (c1 & 127) * 16;
        *(u32x4*)((char*)h_lds + r1 * 2048 + (b1 ^ ((r1 & 7) << 4))) = h1;
        int c2 = tid + 1024; int r2 = c2 >> 7, b2 = (c2 & 127) * 16;
        *(u32x4*)((char*)h_lds + r2 * 2048 + (b2 ^ ((r2 & 7) << 4))) = h2;
        int c3 = tid + 1536; int r3 = c3 >> 7, b3 = (c3 & 127) * 16;
        *(u32x4*)((char*)h_lds + r3 * 2048 + (b3 ^ ((r3 & 7) << 4))) = h3;
      }
      __syncthreads();
      // gates = h @ U : 32 MFMAs split into 2 independent chains
      int arow = l & 15;
      const char* abase = (const char*)h_lds + arow * 2048;
      int sw = (arow & 7) << 4;
      int kres = (l >> 4) << 4;
#pragma unroll
      for (int kb = 0; kb < 32; kb += 2) {
        short8 a0 = *(const short8*)(abase + ((kb * 64 + kres) ^ sw));
        acc0 = mfma16(a0, ufr[kb], acc0);
        short8 a1 = *(const short8*)(abase + (((kb + 1) * 64 + kres) ^ sw));
        acc1 = mfma16(a1, ufr[kb + 1], acc1);
      }
    }
    // gates -> LDS (add xW + bias)
#pragma unroll
    for (int r = 0; r < 4; ++r)
      g_lds[mrow0 + r][g * 32 + jloc] = acc0[r] + acc1[r] + xw[r] + bias_l;
    __syncthreads();
    // pointwise: every thread owns one (row, col)
    float iv = g_lds[prow][pj];
    float fv = g_lds[prow][32 + pj];
    float gv = g_lds[prow][64 + pj];
    float ov = g_lds[prow][96 + pj];
    float si = sigm(iv), sf = sigm(fv), tg = tanhfast(gv), so = sigm(ov);
    float cval = sf * xt + si * tg;
    float hval = so * tanhfast(cval);
    obuf[tid][t & 7] = hval;
    // publish h (coherent, packed 2x bf16 per dword; even-pj lanes store)
    unsigned int me = f2bf(hval);
    unsigned int ot = (unsigned int)__shfl_xor((int)me, 1) & 0xffffu;
    if ((pj & 1) == 0)
      __hip_atomic_store(hbuf + ((t & 1) << 15) + pb * 512 + (pjglob >> 1),
                         me | (ot << 16), __ATOMIC_RELAXED,
                         __HIP_MEMORY_SCOPE_SYSTEM);
    if (t == Seq - 1) {
      out[(size_t)16777216 + (size_t)pb * 1024 + pjglob] = hval;
      out[(size_t)16777216 + 65536 + (size_t)pb * 1024 + pjglob] = cval;
    }
    // release: drain own stores, block barrier, bump tag
    asm volatile("s_waitcnt vmcnt(0)" ::: "memory");
    __syncthreads();
    if (tid == 0)
      __hip_atomic_store(mytag, (unsigned int)(t + 1), __ATOMIC_RELAXED,
                         __HIP_MEMORY_SCOPE_SYSTEM);
    // off critical path: coalesced out flush every 8 steps
    if ((t & 7) == 7) {
      float* dst = out + ((size_t)pb * 1024 + pjglob) * Seq + (t - 7);
#pragma unroll
      for (int q = 0; q < 2; ++q) {
        f32x4 v = {obuf[tid][q * 4], obuf[tid][q * 4 + 1],
                   obuf[tid][q * 4 + 2], obuf[tid][q * 4 + 3]};
        *(f32x4*)(dst + q * 4) = v;
      }
    }
  }
}

extern "C" void kernel_launch(void* const* d_in, const int* in_sizes, int n_in,
                              void* d_out, int out_size, void* d_ws, size_t ws_size,
                              hipStream_t stream) {
  const float* x    = (const float*)d_in[0];
  const float* W    = (const float*)d_in[1];
  const float* U    = (const float*)d_in[2];
  const float* bias = (const float*)d_in[3];
  float* out = (float*)d_out;
  char* ws = (char*)d_ws;

  unsigned short* xs  = (unsigned short*)(ws);                       // 32 MB
  unsigned short* Wbt = (unsigned short*)(ws + (size_t)33554432);    // 8 MB
  unsigned short* Ubt = (unsigned short*)(ws + (size_t)41943040);    // 8 MB
  unsigned short* xWb = (unsigned short*)(ws + (size_t)50331648);    // 128 MB
  unsigned int* hbuf  = (unsigned int*)(ws + (size_t)184549376);     // 256 KB
  unsigned int* tags  = (unsigned int*)(ws + (size_t)184811520);     // [4][32]

  k_tx<<<dim3(Seq / 32, Fd / 32, Bsz), 256, 0, stream>>>(x, xs);
  k_tw<<<dim3(G4 / 32, 1024 / 32), 256, 0, stream>>>(W, Wbt);
  k_tw<<<dim3(G4 / 32, 1024 / 32), 256, 0, stream>>>(U, Ubt);
  k_zero<<<1, 256, 0, stream>>>(tags, 256);
  k_gemm<<<dim3((Mrows / 128) * (G4 / 128)), 256, 0, stream>>>(xs, Wbt, xWb);
  k_rec<<<dim3(128), 512, 0, stream>>>(xs, xWb, Ubt, bias, hbuf, tags, out);
}